// Round 1
// baseline (539.429 us; speedup 1.0000x reference)
//
#include <hip/hip_runtime.h>
#include <hip/hip_cooperative_groups.h>
#include <cstdint>

namespace cg = cooperative_groups;

// Static problem sizes
#define BB 32
#define CC 512
#define NSQ 4096      // N*N
#define SS 128
#define MM 256
#define PP 2080
#define JJ (BB*PP)    // 66560
#define NTILE (JJ/128) // 520 GEMM tiles
#define NJOBS (NTILE + MM)

// ws layout (byte offsets)
#define WS_SN     0         // sents_norm fp32: 128*512*4 = 262144
#define WS_SNB    262144    // sents_norm bf16: 128*512*2 = 131072
#define WS_IDX    393216    // idx: 2080 i32 = 8320
#define WS_IV     401536    // iv_all: 256*128*4 = 131072
#define WS_NEGQ   532608    // neg_sum_q: 128*4 = 512
#define WS_CTR    533120    // job counter: 4

typedef short bf16x8 __attribute__((ext_vector_type(8)));   // 8 bf16 raw (4 VGPRs)
typedef float f32x4  __attribute__((ext_vector_type(4)));   // MFMA accumulator

__device__ __forceinline__ unsigned short f2bf(float x) {
    unsigned int u = __float_as_uint(x);
    unsigned int r = (u + 0x7fffu + ((u >> 16) & 1u)) >> 16;   // RNE
    return (unsigned short)r;
}

#define BK 64
#define LDK 72   // padded k-stride (bf16 elements) -> 144 B rows, 2-way conflicts only

// ---------------------------------------------------------------------------
// Shared-memory union: GEMM tile state / m-job state / prep state
struct SMemG {
    unsigned short sA[128 * LDK];   // sents  [row][k]
    unsigned short vB[128 * LDK];   // video  [col][k]
    int   colb[128];
    int   colflat[128];
    float colrn[128];
    float sqpart[256];
    float red[128][17];
};
struct SMemM {
    float sv[256];
    int   si[256];
    float tvs[512];
    float red[256];
};
struct SMemP {
    float red[256];
};
union SMem { SMemG g; SMemM m; SMemP p; };

// ===========================================================================
// Fused cooperative kernel: prep -> grid.sync -> {520 GEMM tiles + 256 m-jobs
// via dynamic queue} -> grid.sync -> final losses.
// 512 blocks x 256 threads, 2 blocks/CU (48KB LDS, VGPR<=256).
__global__ __launch_bounds__(256, 2)
void k_all(const float* __restrict__ video, const float* __restrict__ sents,
           const float* __restrict__ iou2d, const float* __restrict__ iou2ds,
           float* __restrict__ sn, unsigned short* __restrict__ snb,
           int* __restrict__ idx, float* __restrict__ iv,
           float* __restrict__ negq, int* __restrict__ ctr,
           float* __restrict__ out)
{
    __shared__ SMem sm;
    __shared__ int jobS;
    const int t   = threadIdx.x;
    const int blk = blockIdx.x;
    cg::grid_group grid = cg::this_grid();

    // ------------------------------------------------------------------ phase 0
    if (blk < 128) {
        const float* row = sents + (size_t)blk * CC;
        float x0 = row[t], x1 = row[t + 256];
        sm.p.red[t] = x0 * x0 + x1 * x1;
        __syncthreads();
        for (int off = 128; off > 0; off >>= 1) {
            if (t < off) sm.p.red[t] += sm.p.red[t + off];
            __syncthreads();
        }
        float rn = 1.0f / fmaxf(sqrtf(sm.p.red[0]), 1e-12f);
        float y0 = x0 * rn, y1 = x1 * rn;
        sn[(size_t)blk * CC + t]        = y0;
        sn[(size_t)blk * CC + t + 256]  = y1;
        snb[(size_t)blk * CC + t]       = f2bf(y0);
        snb[(size_t)blk * CC + t + 256] = f2bf(y1);
    } else if (blk < 144) {
        int i = (blk - 128) * 256 + t;      // 0..4095
        int r = i >> 6, c = i & 63;
        if (c >= r) {
            int p = r * 64 - (r * (r - 1)) / 2 + (c - r);
            idx[p] = i;
        }
    } else if (blk == 144) {
        if (t < 128) negq[t] = 0.0f;
        if (t == 128) *ctr = 0;
    }
    grid.sync();

    // ------------------------------------------------------------------ phase 1
    const int w    = t >> 6;          // wave 0..3
    const int lane = t & 63;
    const int q    = lane >> 4;       // quad 0..3
    const int l15  = lane & 15;

    for (;;) {
        __syncthreads();              // protects sm reuse across jobs
        if (t == 0) jobS = atomicAdd(ctr, 1);
        __syncthreads();
        const int job = jobS;
        if (job >= NJOBS) break;

        if (job < NTILE) {
            // ---------------- GEMM tile: 128(S) x 128(cols) of score matrix
            const int j0 = job * 128;
            if (t < 128) {
                int col = j0 + t;
                int b = col / PP;
                sm.g.colb[t] = b;
                sm.g.colflat[t] = idx[col - b * PP];
            }
            // loader identity: column jj, k-half kh (32 channels each)
            const int jj = t & 127;
            const int kh = t >> 7;
            int colL = j0 + jj;
            int bL = colL / PP;
            int flatL = idx[colL - bL * PP];
            const float* vbase = video + (size_t)bL * (CC * NSQ) + flatL;

            f32x4 acc[2][8];
#pragma unroll
            for (int i = 0; i < 2; i++)
#pragma unroll
                for (int j = 0; j < 8; j++) acc[i][j] = (f32x4){0.f, 0.f, 0.f, 0.f};
            float sqa = 0.f;

            // prefetch K-step 0 into registers (T14 async-stage split)
            float pre[32];
            {
                const float* vp = vbase + (size_t)(kh * 32) * NSQ;
#pragma unroll
                for (int i = 0; i < 32; i++) pre[i] = vp[(size_t)i * NSQ];
            }

            for (int k0 = 0; k0 < CC; k0 += BK) {
                __syncthreads();
                // stage A: 128 rows x 64 k of bf16 sents (L2-resident)
#pragma unroll
                for (int it = 0; it < 4; it++) {
                    int lin = t + it * 256;
                    int row = lin >> 3, kc = (lin & 7) * 8;
                    bf16x8 v = *(const bf16x8*)(snb + (size_t)row * CC + k0 + kc);
                    *(bf16x8*)(sm.g.sA + row * LDK + kc) = v;
                }
                // stage B: convert prefetched fp32 -> bf16, fused sumsq
#pragma unroll
                for (int g = 0; g < 4; g++) {
                    unsigned short buf[8];
#pragma unroll
                    for (int i = 0; i < 8; i++) {
                        float x = pre[g * 8 + i];
                        sqa += x * x;
                        buf[i] = f2bf(x);
                    }
                    *(bf16x8*)(sm.g.vB + jj * LDK + kh * 32 + g * 8) = *(bf16x8*)buf;
                }
                __syncthreads();
                // issue next K-step's gathers: latency hides under MFMA below
                if (k0 + BK < CC) {
                    const float* vp = vbase + (size_t)(k0 + BK + kh * 32) * NSQ;
#pragma unroll
                    for (int i = 0; i < 32; i++) pre[i] = vp[(size_t)i * NSQ];
                }
                // compute: two K=32 sub-steps
#pragma unroll
                for (int ks = 0; ks < BK; ks += 32) {
                    bf16x8 a[2], bfr[8];
#pragma unroll
                    for (int rt = 0; rt < 2; rt++) {
                        int row = w * 32 + rt * 16 + l15;
                        a[rt] = *(const bf16x8*)(sm.g.sA + row * LDK + ks + q * 8);
                    }
#pragma unroll
                    for (int ct = 0; ct < 8; ct++) {
                        int col = ct * 16 + l15;
                        bfr[ct] = *(const bf16x8*)(sm.g.vB + col * LDK + ks + q * 8);
                    }
#pragma unroll
                    for (int rt = 0; rt < 2; rt++)
#pragma unroll
                        for (int ct = 0; ct < 8; ct++)
                            acc[rt][ct] = __builtin_amdgcn_mfma_f32_16x16x32_bf16(
                                a[rt], bfr[ct], acc[rt][ct], 0, 0, 0);
                }
            }

            // column reciprocal norms (fp32)
            sm.g.sqpart[t] = sqa;
            __syncthreads();
            if (t < 128)
                sm.g.colrn[t] = 1.0f / fmaxf(sqrtf(sm.g.sqpart[t] + sm.g.sqpart[t + 128]), 1e-12f);
            __syncthreads();

            // epilogue: scale, exp, mask, per-row partials
            // D layout: row = rt*16 + q*4 + reg (+ w*32), col = ct*16 + l15
#pragma unroll
            for (int rt = 0; rt < 2; rt++) {
#pragma unroll
                for (int r = 0; r < 4; r++) {
                    int s = w * 32 + rt * 16 + q * 4 + r;
                    float rowsum = 0.f;
#pragma unroll
                    for (int ct = 0; ct < 8; ct++) {
                        int c = ct * 16 + l15;
                        float sc = acc[rt][ct][r] * sm.g.colrn[c];
                        float e = expf(sc * 10.0f);            // / T_TEMP
                        if ((s >> 2) == sm.g.colb[c]) {        // same-video block
                            if (iou2d[(size_t)s * NSQ + sm.g.colflat[c]] > 0.5f) e = 0.f;
                        }
                        rowsum += e;
                    }
                    sm.g.red[s][l15] = rowsum;   // unique (s,l15) per lane
                }
            }
            __syncthreads();
            if (t < 128) {
                float tot = 0.f;
#pragma unroll
                for (int x = 0; x < 16; x++) tot += sm.g.red[t][x];
                atomicAdd(&negq[t], tot);
            }
        } else {
            // ---------------- m-job: argmax over P, gather+normalize, iv row
            const int m = job - NTILE;
            {
                float best = -1e30f; int bi = 1 << 30;
                const float* row = iou2ds + (size_t)m * NSQ;
                for (int p = t; p < PP; p += 256) {
                    float v = row[idx[p]];
                    if (v > best || (v == best && p < bi)) { best = v; bi = p; }
                }
                sm.m.sv[t] = best; sm.m.si[t] = bi;
                __syncthreads();
                for (int off = 128; off > 0; off >>= 1) {
                    if (t < off) {
                        float v2 = sm.m.sv[t + off]; int i2 = sm.m.si[t + off];
                        if (v2 > sm.m.sv[t] || (v2 == sm.m.sv[t] && i2 < sm.m.si[t])) {
                            sm.m.sv[t] = v2; sm.m.si[t] = i2;
                        }
                    }
                    __syncthreads();
                }
            }
            const int flat = idx[sm.m.si[0]];
            const int b = m >> 3;                     // scatter_m2v

            const float* base = video + (size_t)b * CC * NSQ + flat;
            float x0 = base[(size_t)t * NSQ];
            float x1 = base[(size_t)(t + 256) * NSQ];
            sm.m.red[t] = x0 * x0 + x1 * x1;
            __syncthreads();
            for (int off = 128; off > 0; off >>= 1) {
                if (t < off) sm.m.red[t] += sm.m.red[t + off];
                __syncthreads();
            }
            float rn = 1.0f / fmaxf(sqrtf(sm.m.red[0]), 1e-12f);
            sm.m.tvs[t] = x0 * rn;
            sm.m.tvs[t + 256] = x1 * rn;
            __syncthreads();

            const int s = t & 127, h = t >> 7;
            const float4* a4 = (const float4*)(sm.m.tvs + h * 256);
            const float4* b4 = (const float4*)(sn + (size_t)s * CC + h * 256);
            float acc2 = 0.f;
#pragma unroll 8
            for (int c = 0; c < 64; c++) {
                float4 a = a4[c], bb = b4[c];
                acc2 += a.x * bb.x + a.y * bb.y + a.z * bb.z + a.w * bb.w;
            }
            __syncthreads();          // red reuse
            sm.m.red[t] = acc2;
            __syncthreads();
            if (t < 128) iv[(size_t)m * SS + t] = sm.m.red[t] + sm.m.red[t + 128];
        }
    }
    grid.sync();

    // ------------------------------------------------------------------ phase 2
    if (blk == 0) {
        const float* row = iv + (size_t)t * SS;
        const int ms = t >> 1;       // scatter_m2s
        float pos = row[ms];
        float nv = 0.f;
        for (int s2 = 0; s2 < SS; s2++) {
            float e = expf(row[s2] * 10.0f);
            if (s2 == ms) e = 0.f;
            nv += e;
        }
        float pe = expf(pos * 10.0f);
        float lv = logf(pe + nv) - pos * 10.0f;
        float lq = logf(pe + negq[ms]) - pos * 10.0f;
        sm.m.sv[t] = lv; sm.m.red[t] = lq;
        __syncthreads();
        for (int off = 128; off > 0; off >>= 1) {
            if (t < off) { sm.m.sv[t] += sm.m.sv[t + off]; sm.m.red[t] += sm.m.red[t + off]; }
            __syncthreads();
        }
        if (t == 0) {
            float liv = sm.m.sv[0] / 256.f, liq = sm.m.red[0] / 256.f;
            out[0] = liv + liq;   // total (WEIGHT=1)
            out[1] = liv;
            out[2] = liq;
        }
    }
}

// ===========================================================================
// Legacy 4-kernel fallback (known-good) in case cooperative launch is refused.
__global__ void k_prep(const float* __restrict__ sents, float* __restrict__ sn,
                       unsigned short* __restrict__ snb,
                       int* __restrict__ idx, float* __restrict__ negq) {
    const int blk = blockIdx.x, t = threadIdx.x;
    if (blk < 128) {
        __shared__ float red[256];
        const float* row = sents + (size_t)blk * CC;
        float x0 = row[t], x1 = row[t + 256];
        red[t] = x0 * x0 + x1 * x1;
        __syncthreads();
        for (int off = 128; off > 0; off >>= 1) {
            if (t < off) red[t] += red[t + off];
            __syncthreads();
        }
        float rn = 1.0f / fmaxf(sqrtf(red[0]), 1e-12f);
        float y0 = x0 * rn, y1 = x1 * rn;
        sn[(size_t)blk * CC + t]        = y0;
        sn[(size_t)blk * CC + t + 256]  = y1;
        snb[(size_t)blk * CC + t]       = f2bf(y0);
        snb[(size_t)blk * CC + t + 256] = f2bf(y1);
    } else if (blk < 144) {
        int i = (blk - 128) * 256 + t;
        int r = i >> 6, c = i & 63;
        if (c >= r) {
            int p = r * 64 - (r * (r - 1)) / 2 + (c - r);
            idx[p] = i;
        }
    } else {
        if (t < 128) negq[t] = 0.0f;
    }
}

__global__ void k_fused(const float* __restrict__ video, const float* __restrict__ sn,
                        const float* __restrict__ iou2ds, const int* __restrict__ idx,
                        float* __restrict__ iv) {
    const int m = blockIdx.x, t = threadIdx.x;
    __shared__ float sv[256];
    __shared__ int   si[256];
    __shared__ float tvs[512];
    __shared__ float red[256];
    {
        float best = -1e30f; int bi = 1 << 30;
        const float* row = iou2ds + (size_t)m * NSQ;
        for (int p = t; p < PP; p += 256) {
            float v = row[idx[p]];
            if (v > best || (v == best && p < bi)) { best = v; bi = p; }
        }
        sv[t] = best; si[t] = bi;
        __syncthreads();
        for (int off = 128; off > 0; off >>= 1) {
            if (t < off) {
                float v2 = sv[t + off]; int i2 = si[t + off];
                if (v2 > sv[t] || (v2 == sv[t] && i2 < si[t])) { sv[t] = v2; si[t] = i2; }
            }
            __syncthreads();
        }
    }
    const int flat = idx[si[0]];
    const int b = m >> 3;
    const float* base = video + (size_t)b * CC * NSQ + flat;
    float x0 = base[(size_t)t * NSQ];
    float x1 = base[(size_t)(t + 256) * NSQ];
    red[t] = x0 * x0 + x1 * x1;
    __syncthreads();
    for (int off = 128; off > 0; off >>= 1) {
        if (t < off) red[t] += red[t + off];
        __syncthreads();
    }
    float rn = 1.0f / fmaxf(sqrtf(red[0]), 1e-12f);
    tvs[t] = x0 * rn;
    tvs[t + 256] = x1 * rn;
    __syncthreads();
    const int s = t & 127, h = t >> 7;
    const float4* a4 = (const float4*)(tvs + h * 256);
    const float4* b4 = (const float4*)(sn + (size_t)s * CC + h * 256);
    float acc = 0.f;
#pragma unroll 8
    for (int c = 0; c < 64; c++) {
        float4 a = a4[c], bb = b4[c];
        acc += a.x * bb.x + a.y * bb.y + a.z * bb.z + a.w * bb.w;
    }
    __syncthreads();
    red[t] = acc;
    __syncthreads();
    if (t < 128) iv[(size_t)m * SS + t] = red[t] + red[t + 128];
}

__global__ __launch_bounds__(256)
void k_big(const float* __restrict__ video, const unsigned short* __restrict__ snb,
           const float* __restrict__ iou2d, const int* __restrict__ idx,
           float* __restrict__ negq) {
    __shared__ unsigned short sA[128 * LDK];
    __shared__ unsigned short vB[128 * LDK];
    __shared__ int   colb[128], colflat[128];
    __shared__ float colrn[128];
    __shared__ float sqpart[256];
    __shared__ float red[128][17];

    const int t    = threadIdx.x;
    const int w    = t >> 6;
    const int lane = t & 63;
    const int q    = lane >> 4;
    const int l15  = lane & 15;
    const int j0   = blockIdx.x * 128;

    if (t < 128) {
        int col = j0 + t;
        int b = col / PP;
        colb[t] = b;
        colflat[t] = idx[col - b * PP];
    }
    const int jj = t & 127;
    const int kh = t >> 7;
    int colL = j0 + jj;
    int bL = colL / PP;
    int flatL = idx[colL - bL * PP];
    const float* vbase = video + (size_t)bL * (CC * NSQ) + flatL;

    f32x4 acc[2][8];
#pragma unroll
    for (int i = 0; i < 2; i++)
#pragma unroll
        for (int j = 0; j < 8; j++) acc[i][j] = (f32x4){0.f, 0.f, 0.f, 0.f};
    float sqa = 0.f;

    for (int k0 = 0; k0 < CC; k0 += BK) {
        __syncthreads();
#pragma unroll
        for (int it = 0; it < 4; it++) {
            int lin = t + it * 256;
            int row = lin >> 3, kc = (lin & 7) * 8;
            bf16x8 v = *(const bf16x8*)(snb + (size_t)row * CC + k0 + kc);
            *(bf16x8*)(sA + row * LDK + kc) = v;
        }
        {
            const float* vp = vbase + (size_t)(k0 + kh * 32) * NSQ;
#pragma unroll
            for (int g = 0; g < 4; g++) {
                unsigned short buf[8];
#pragma unroll
                for (int i = 0; i < 8; i++) {
                    float x = vp[(size_t)(g * 8 + i) * NSQ];
                    sqa += x * x;
                    buf[i] = f2bf(x);
                }
                *(bf16x8*)(vB + jj * LDK + kh * 32 + g * 8) = *(bf16x8*)buf;
            }
        }
        __syncthreads();
#pragma unroll
        for (int ks = 0; ks < BK; ks += 32) {
            bf16x8 a[2], bfr[8];
#pragma unroll
            for (int rt = 0; rt < 2; rt++) {
                int row = w * 32 + rt * 16 + l15;
                a[rt] = *(const bf16x8*)(sA + row * LDK + ks + q * 8);
            }
#pragma unroll
            for (int ct = 0; ct < 8; ct++) {
                int col = ct * 16 + l15;
                bfr[ct] = *(const bf16x8*)(vB + col * LDK + ks + q * 8);
            }
#pragma unroll
            for (int rt = 0; rt < 2; rt++)
#pragma unroll
                for (int ct = 0; ct < 8; ct++)
                    acc[rt][ct] = __builtin_amdgcn_mfma_f32_16x16x32_bf16(
                        a[rt], bfr[ct], acc[rt][ct], 0, 0, 0);
        }
    }

    sqpart[t] = sqa;
    __syncthreads();
    if (t < 128) colrn[t] = 1.0f / fmaxf(sqrtf(sqpart[t] + sqpart[t + 128]), 1e-12f);
    __syncthreads();

#pragma unroll
    for (int rt = 0; rt < 2; rt++) {
#pragma unroll
        for (int r = 0; r < 4; r++) {
            int s = w * 32 + rt * 16 + q * 4 + r;
            float rowsum = 0.f;
#pragma unroll
            for (int ct = 0; ct < 8; ct++) {
                int c = ct * 16 + l15;
                float sc = acc[rt][ct][r] * colrn[c];
                float e = expf(sc * 10.0f);
                if ((s >> 2) == colb[c]) {
                    if (iou2d[(size_t)s * NSQ + colflat[c]] > 0.5f) e = 0.f;
                }
                rowsum += e;
            }
            red[s][l15] = rowsum;
        }
    }
    __syncthreads();
    if (t < 128) {
        float tot = 0.f;
#pragma unroll
        for (int x = 0; x < 16; x++) tot += red[t][x];
        atomicAdd(&negq[t], tot);
    }
}

__global__ void k_final(const float* __restrict__ iv, const float* __restrict__ negq,
                        float* __restrict__ out) {
    const int t = threadIdx.x;
    __shared__ float rv[256], rq[256];
    const float* row = iv + (size_t)t * SS;
    const int ms = t >> 1;
    float pos = row[ms];
    float nv = 0.f;
    for (int s = 0; s < SS; s++) {
        float e = expf(row[s] * 10.0f);
        if (s == ms) e = 0.f;
        nv += e;
    }
    float pe = expf(pos * 10.0f);
    float lv = logf(pe + nv) - pos * 10.0f;
    float lq = logf(pe + negq[ms]) - pos * 10.0f;
    rv[t] = lv; rq[t] = lq;
    __syncthreads();
    for (int off = 128; off > 0; off >>= 1) {
        if (t < off) { rv[t] += rv[t + off]; rq[t] += rq[t + off]; }
        __syncthreads();
    }
    if (t == 0) {
        float liv = rv[0] / 256.f, liq = rq[0] / 256.f;
        out[0] = liv + liq;
        out[1] = liv;
        out[2] = liq;
    }
}

// ---------------------------------------------------------------------------
extern "C" void kernel_launch(void* const* d_in, const int* in_sizes, int n_in,
                              void* d_out, int out_size, void* d_ws, size_t ws_size,
                              hipStream_t stream) {
    const float* video  = (const float*)d_in[0];   // (B,C,N,N)
    const float* sents  = (const float*)d_in[1];   // (S,C)
    const float* iou2d  = (const float*)d_in[4];   // (S,N,N)
    const float* iou2ds = (const float*)d_in[5];   // (M,N,N)
    float* out = (float*)d_out;

    char* ws = (char*)d_ws;
    float*          sn   = (float*)(ws + WS_SN);
    unsigned short* snb  = (unsigned short*)(ws + WS_SNB);
    int*            idx  = (int*)(ws + WS_IDX);
    float*          iv   = (float*)(ws + WS_IV);
    float*          negq = (float*)(ws + WS_NEGQ);
    int*            ctr  = (int*)(ws + WS_CTR);

    void* args[] = { (void*)&video, (void*)&sents, (void*)&iou2d, (void*)&iou2ds,
                     (void*)&sn, (void*)&snb, (void*)&idx, (void*)&iv,
                     (void*)&negq, (void*)&ctr, (void*)&out };
    hipError_t err = hipLaunchCooperativeKernel((const void*)k_all, dim3(512), dim3(256),
                                                args, 0, stream);
    if (err != hipSuccess) {
        // fallback: proven 4-kernel path
        k_prep <<<145, 256, 0, stream>>>(sents, sn, snb, idx, negq);
        k_big  <<<JJ / 128, 256, 0, stream>>>(video, snb, iou2d, idx, negq);
        k_fused<<<MM,  256, 0, stream>>>(video, sn, iou2ds, idx, iv);
        k_final<<<1,   256, 0, stream>>>(iv, negq, out);
    }
}

// Round 2
// 420.966 us; speedup vs baseline: 1.2814x; 1.2814x over previous
//
#include <hip/hip_runtime.h>
#include <cstdint>

// Static problem sizes
#define BB 32
#define CC 512
#define NSQ 4096      // N*N
#define SS 128
#define MM 256
#define PP 2080

// ws layout (byte offsets)
#define WS_SN     0         // sents_norm fp32: 128*512*4 = 262144
#define WS_SNB    262144    // sents_norm bf16: 128*512*2 = 131072
#define WS_IDX    393216    // idx: 2080 i32 = 8320
#define WS_IV     401536    // iv_all: 256*128*4 = 131072
#define WS_NEGQ   532608    // neg_sum_q: 128*4 = 512

typedef short bf16x8 __attribute__((ext_vector_type(8)));   // 8 bf16 raw (4 VGPRs)
typedef float f32x4  __attribute__((ext_vector_type(4)));   // MFMA accumulator

__device__ __forceinline__ unsigned short f2bf(float x) {
    unsigned int u = __float_as_uint(x);
    unsigned int r = (u + 0x7fffu + ((u >> 16) & 1u)) >> 16;   // RNE
    return (unsigned short)r;
}

// ---------------------------------------------------------------------------
// prep: blocks 0..127 normalize sents rows (fp32 + bf16 copies);
//       128..143 build idx table (k_fused only); 144 zeroes negq.
__global__ void k_prep(const float* __restrict__ sents, float* __restrict__ sn,
                       unsigned short* __restrict__ snb,
                       int* __restrict__ idx, float* __restrict__ negq) {
    const int blk = blockIdx.x, t = threadIdx.x;
    if (blk < 128) {
        __shared__ float red[256];
        const float* row = sents + (size_t)blk * CC;
        float x0 = row[t], x1 = row[t + 256];
        red[t] = x0 * x0 + x1 * x1;
        __syncthreads();
        for (int off = 128; off > 0; off >>= 1) {
            if (t < off) red[t] += red[t + off];
            __syncthreads();
        }
        float rn = 1.0f / fmaxf(sqrtf(red[0]), 1e-12f);
        float y0 = x0 * rn, y1 = x1 * rn;
        sn[(size_t)blk * CC + t]        = y0;
        sn[(size_t)blk * CC + t + 256]  = y1;
        snb[(size_t)blk * CC + t]       = f2bf(y0);
        snb[(size_t)blk * CC + t + 256] = f2bf(y1);
    } else if (blk < 144) {
        int i = (blk - 128) * 256 + t;      // 0..4095
        int r = i >> 6, c = i & 63;
        if (c >= r) {
            int p = r * 64 - (r * (r - 1)) / 2 + (c - r);
            idx[p] = i;
        }
    } else {
        if (t < 128) negq[t] = 0.0f;
    }
}

// ---------------------------------------------------------------------------
// Dense big GEMM: one block = one video b x 128 consecutive proposal columns
// (ALL 4096 N*N columns computed; lower-triangle masked in epilogue).
// B-operand loads are dense float4 streams; [k][col]->[col][k] transpose done
// via bf16-pair packing + ds_write_b32. Epilogue: rnorm, masked exp, row
// partials, atomicAdd negq[s].
#define BK 64
#define LDK 72   // padded k-stride (bf16) -> 144B rows; keeps b128 frags 16B-aligned

__global__ __launch_bounds__(256)
void k_bigd(const float* __restrict__ video, const unsigned short* __restrict__ snb,
            const float* __restrict__ iou2d, float* __restrict__ negq) {
    __shared__ char smem[36864];
    unsigned short* sA = (unsigned short*)smem;            // [128 rows][LDK]
    unsigned short* vB = (unsigned short*)(smem + 18432);  // [128 cols][LDK]

    const int t    = threadIdx.x;
    const int w    = t >> 6;          // wave 0..3
    const int lane = t & 63;
    const int q    = lane >> 4;       // quad 0..3
    const int l15  = lane & 15;

    const int b  = blockIdx.x >> 5;          // video (tiles never cross videos)
    const int j0 = (blockIdx.x & 31) * 128;  // first flat column of tile

    const int cg = t & 31;            // column group: cols 4cg..4cg+3
    const int kr = t >> 5;            // 0..7

    f32x4 acc[2][8];
#pragma unroll
    for (int i = 0; i < 2; i++)
#pragma unroll
        for (int j = 0; j < 8; j++) acc[i][j] = (f32x4){0.f, 0.f, 0.f, 0.f};
    float sq0 = 0.f, sq1 = 0.f, sq2 = 0.f, sq3 = 0.f;   // per-col sumsq partials

    for (int k0 = 0; k0 < CC; k0 += BK) {
        __syncthreads();
        // stage A: 128 sent-rows x 64 k of bf16 (L2-resident snb)
#pragma unroll
        for (int it = 0; it < 4; it++) {
            int lin = t + it * 256;
            int row = lin >> 3, kc = (lin & 7) * 8;
            bf16x8 v = *(const bf16x8*)(snb + (size_t)row * CC + k0 + kc);
            *(bf16x8*)(sA + row * LDK + kc) = v;
        }
        // stage B: dense video loads — 8 float4/thread (4 k-pairs x 4 cols)
        float4 r0[4], r1[4];
#pragma unroll
        for (int i = 0; i < 4; i++) {
            int k = 2 * (kr + 8 * i);
            const float* p = video + ((size_t)b * CC + k0 + k) * NSQ + j0 + 4 * cg;
            r0[i] = *(const float4*)p;
            r1[i] = *(const float4*)(p + NSQ);
        }
        // convert + transpose-pack: (k,k+1) bf16 pair per column -> u32 write
#pragma unroll
        for (int i = 0; i < 4; i++) {
            int kp = kr + 8 * i;      // k-pair index 0..31
            sq0 += r0[i].x * r0[i].x + r1[i].x * r1[i].x;
            sq1 += r0[i].y * r0[i].y + r1[i].y * r1[i].y;
            sq2 += r0[i].z * r0[i].z + r1[i].z * r1[i].z;
            sq3 += r0[i].w * r0[i].w + r1[i].w * r1[i].w;
            unsigned int p0 = (unsigned int)f2bf(r0[i].x) | ((unsigned int)f2bf(r1[i].x) << 16);
            unsigned int p1 = (unsigned int)f2bf(r0[i].y) | ((unsigned int)f2bf(r1[i].y) << 16);
            unsigned int p2 = (unsigned int)f2bf(r0[i].z) | ((unsigned int)f2bf(r1[i].z) << 16);
            unsigned int p3 = (unsigned int)f2bf(r0[i].w) | ((unsigned int)f2bf(r1[i].w) << 16);
            *(unsigned int*)(vB + (4 * cg + 0) * LDK + 2 * kp) = p0;
            *(unsigned int*)(vB + (4 * cg + 1) * LDK + 2 * kp) = p1;
            *(unsigned int*)(vB + (4 * cg + 2) * LDK + 2 * kp) = p2;
            *(unsigned int*)(vB + (4 * cg + 3) * LDK + 2 * kp) = p3;
        }
        __syncthreads();
        // compute: two K=32 sub-steps
#pragma unroll
        for (int ks = 0; ks < BK; ks += 32) {
            bf16x8 a[2], bfr[8];
#pragma unroll
            for (int rt = 0; rt < 2; rt++) {
                int row = w * 32 + rt * 16 + l15;
                a[rt] = *(const bf16x8*)(sA + row * LDK + ks + q * 8);
            }
#pragma unroll
            for (int ct = 0; ct < 8; ct++) {
                int col = ct * 16 + l15;
                bfr[ct] = *(const bf16x8*)(vB + col * LDK + ks + q * 8);
            }
#pragma unroll
            for (int rt = 0; rt < 2; rt++)
#pragma unroll
                for (int ct = 0; ct < 8; ct++)
                    acc[rt][ct] = __builtin_amdgcn_mfma_f32_16x16x32_bf16(
                        a[rt], bfr[ct], acc[rt][ct], 0, 0, 0);
        }
    }
    __syncthreads();   // tile buffers dead; overlay epilogue buffers

    float* sqred = (float*)smem;             // [128][9]  = 4608 B
    float* redp  = (float*)(smem + 4608);    // [128][17] = 8704 B
    float* colrn = (float*)(smem + 13312);   // [128]     = 512 B

    sqred[(4 * cg + 0) * 9 + kr] = sq0;
    sqred[(4 * cg + 1) * 9 + kr] = sq1;
    sqred[(4 * cg + 2) * 9 + kr] = sq2;
    sqred[(4 * cg + 3) * 9 + kr] = sq3;
    __syncthreads();
    if (t < 128) {
        float ssum = 0.f;
#pragma unroll
        for (int x = 0; x < 8; x++) ssum += sqred[t * 9 + x];
        colrn[t] = 1.0f / fmaxf(sqrtf(ssum), 1e-12f);
    }
    __syncthreads();

    // epilogue: D layout row = w*32 + rt*16 + q*4 + r, col = ct*16 + l15
#pragma unroll
    for (int rt = 0; rt < 2; rt++) {
#pragma unroll
        for (int r = 0; r < 4; r++) {
            int s = w * 32 + rt * 16 + q * 4 + r;
            bool myvid = ((s >> 2) == b);     // uniform video per tile
            float rowsum = 0.f;
#pragma unroll
            for (int ct = 0; ct < 8; ct++) {
                int c = ct * 16 + l15;
                int j = j0 + c;                       // flat N*N index
                bool valid = (j & 63) >= (j >> 6);    // upper triangle
                float e = 0.f;
                if (valid) {
                    float sc = acc[rt][ct][r] * colrn[c];
                    e = expf(sc * 10.0f);             // / T_TEMP
                    if (myvid && iou2d[(size_t)s * NSQ + j] > 0.5f) e = 0.f;
                }
                rowsum += e;
            }
            redp[s * 17 + l15] = rowsum;   // unique (s,l15) per lane
        }
    }
    __syncthreads();
    if (t < 128) {
        float tot = 0.f;
#pragma unroll
        for (int x = 0; x < 16; x++) tot += redp[t * 17 + x];
        atomicAdd(&negq[t], tot);
    }
}

// ---------------------------------------------------------------------------
// fused per-target kernel: argmax over P, gather+normalize top column,
// then iv[m][s] = dot(topcol_norm, sn[s]) for all 128 sentences.
__global__ void k_fused(const float* __restrict__ video, const float* __restrict__ sn,
                        const float* __restrict__ iou2ds, const int* __restrict__ idx,
                        float* __restrict__ iv) {
    const int m = blockIdx.x, t = threadIdx.x;   // 256 threads
    __shared__ float sv[256];
    __shared__ int   si[256];
    __shared__ float tvs[512];
    __shared__ float red[256];

    // --- argmax of iou2ds[m] over valid proposals (tie -> lowest p)
    {
        float best = -1e30f; int bi = 1 << 30;
        const float* row = iou2ds + (size_t)m * NSQ;
        for (int p = t; p < PP; p += 256) {
            float v = row[idx[p]];
            if (v > best || (v == best && p < bi)) { best = v; bi = p; }
        }
        sv[t] = best; si[t] = bi;
        __syncthreads();
        for (int off = 128; off > 0; off >>= 1) {
            if (t < off) {
                float v2 = sv[t + off]; int i2 = si[t + off];
                if (v2 > sv[t] || (v2 == sv[t] && i2 < si[t])) { sv[t] = v2; si[t] = i2; }
            }
            __syncthreads();
        }
    }
    const int flat = idx[si[0]];
    const int b = m >> 3;                     // scatter_m2v

    // --- gather + normalize the column
    const float* base = video + (size_t)b * CC * NSQ + flat;
    float x0 = base[(size_t)t * NSQ];
    float x1 = base[(size_t)(t + 256) * NSQ];
    red[t] = x0 * x0 + x1 * x1;
    __syncthreads();
    for (int off = 128; off > 0; off >>= 1) {
        if (t < off) red[t] += red[t + off];
        __syncthreads();
    }
    float rn = 1.0f / fmaxf(sqrtf(red[0]), 1e-12f);
    tvs[t] = x0 * rn;
    tvs[t + 256] = x1 * rn;
    __syncthreads();

    // --- iv row: thread (s = t&127, h = t>>7) computes half-dot
    const int s = t & 127, h = t >> 7;
    const float4* a4 = (const float4*)(tvs + h * 256);
    const float4* b4 = (const float4*)(sn + (size_t)s * CC + h * 256);
    float acc = 0.f;
#pragma unroll 8
    for (int c = 0; c < 64; c++) {
        float4 a = a4[c], bb = b4[c];
        acc += a.x * bb.x + a.y * bb.y + a.z * bb.z + a.w * bb.w;
    }
    __syncthreads();          // red reuse
    red[t] = acc;
    __syncthreads();
    if (t < 128) iv[(size_t)m * SS + t] = red[t] + red[t + 128];
}

// ---------------------------------------------------------------------------
// final losses
__global__ void k_final(const float* __restrict__ iv, const float* __restrict__ negq,
                        float* __restrict__ out) {
    const int t = threadIdx.x;   // 256 = M
    __shared__ float rv[256], rq[256];
    const float* row = iv + (size_t)t * SS;
    const int ms = t >> 1;       // scatter_m2s
    float pos = row[ms];
    float nv = 0.f;
    for (int s = 0; s < SS; s++) {
        float e = expf(row[s] * 10.0f);
        if (s == ms) e = 0.f;
        nv += e;
    }
    float pe = expf(pos * 10.0f);
    float lv = logf(pe + nv) - pos * 10.0f;
    float lq = logf(pe + negq[ms]) - pos * 10.0f;
    rv[t] = lv; rq[t] = lq;
    __syncthreads();
    for (int off = 128; off > 0; off >>= 1) {
        if (t < off) { rv[t] += rv[t + off]; rq[t] += rq[t + off]; }
        __syncthreads();
    }
    if (t == 0) {
        float liv = rv[0] / 256.f, liq = rq[0] / 256.f;
        out[0] = liv + liq;   // total (WEIGHT=1)
        out[1] = liv;
        out[2] = liq;
    }
}

// ---------------------------------------------------------------------------
extern "C" void kernel_launch(void* const* d_in, const int* in_sizes, int n_in,
                              void* d_out, int out_size, void* d_ws, size_t ws_size,
                              hipStream_t stream) {
    const float* video  = (const float*)d_in[0];   // (B,C,N,N)
    const float* sents  = (const float*)d_in[1];   // (S,C)
    const float* iou2d  = (const float*)d_in[4];   // (S,N,N)
    const float* iou2ds = (const float*)d_in[5];   // (M,N,N)
    float* out = (float*)d_out;

    char* ws = (char*)d_ws;
    float*          sn   = (float*)(ws + WS_SN);
    unsigned short* snb  = (unsigned short*)(ws + WS_SNB);
    int*            idx  = (int*)(ws + WS_IDX);
    float*          iv   = (float*)(ws + WS_IV);
    float*          negq = (float*)(ws + WS_NEGQ);

    k_prep <<<145, 256, 0, stream>>>(sents, sn, snb, idx, negq);
    k_bigd <<<BB * 32, 256, 0, stream>>>(video, snb, iou2d, negq);
    k_fused<<<MM, 256, 0, stream>>>(video, sn, iou2ds, idx, iv);
    k_final<<<1, 256, 0, stream>>>(iv, negq, out);
}

// Round 3
// 420.417 us; speedup vs baseline: 1.2831x; 1.0013x over previous
//
#include <hip/hip_runtime.h>
#include <cstdint>

// Static problem sizes
#define BB 32
#define CC 512
#define NSQ 4096      // N*N
#define SS 128
#define MM 256
#define PP 2080

// ws layout (byte offsets)
#define WS_SN     0         // sents_norm fp32: 128*512*4 = 262144
#define WS_SNB    262144    // sents_norm bf16: 128*512*2 = 131072
#define WS_IDX    393216    // idx: 2080 i32 = 8320
#define WS_IV     401536    // iv_all: 256*128*4 = 131072
#define WS_NEGQ   532608    // neg_sum_q: 128*4 = 512

typedef short bf16x8 __attribute__((ext_vector_type(8)));   // 8 bf16 raw (4 VGPRs)
typedef float f32x4  __attribute__((ext_vector_type(4)));   // MFMA accumulator

__device__ __forceinline__ unsigned short f2bf(float x) {
    unsigned int u = __float_as_uint(x);
    unsigned int r = (u + 0x7fffu + ((u >> 16) & 1u)) >> 16;   // RNE
    return (unsigned short)r;
}

// ---------------------------------------------------------------------------
// prep: blocks 0..127 normalize sents rows (fp32 + bf16 copies);
//       128..143 build idx table (m-jobs only); 144 zeroes negq.
__global__ void k_prep(const float* __restrict__ sents, float* __restrict__ sn,
                       unsigned short* __restrict__ snb,
                       int* __restrict__ idx, float* __restrict__ negq) {
    const int blk = blockIdx.x, t = threadIdx.x;
    if (blk < 128) {
        __shared__ float red[256];
        const float* row = sents + (size_t)blk * CC;
        float x0 = row[t], x1 = row[t + 256];
        red[t] = x0 * x0 + x1 * x1;
        __syncthreads();
        for (int off = 128; off > 0; off >>= 1) {
            if (t < off) red[t] += red[t + off];
            __syncthreads();
        }
        float rn = 1.0f / fmaxf(sqrtf(red[0]), 1e-12f);
        float y0 = x0 * rn, y1 = x1 * rn;
        sn[(size_t)blk * CC + t]        = y0;
        sn[(size_t)blk * CC + t + 256]  = y1;
        snb[(size_t)blk * CC + t]       = f2bf(y0);
        snb[(size_t)blk * CC + t + 256] = f2bf(y1);
    } else if (blk < 144) {
        int i = (blk - 128) * 256 + t;      // 0..4095
        int r = i >> 6, c = i & 63;
        if (c >= r) {
            int p = r * 64 - (r * (r - 1)) / 2 + (c - r);
            idx[p] = i;
        }
    } else {
        if (t < 128) negq[t] = 0.0f;
    }
}

// ---------------------------------------------------------------------------
// Merged big kernel.
// Blocks 0..1023: dense score-GEMM tile = one video b x 128 consecutive flat
//   columns (lower triangle masked in epilogue). B-operand: each lane owns one
//   column, loads k-scalars (wave-coalesced 256B), packs bf16x8, writes
//   ds_write_b128 -> bank-conflict-free [col][k] LDS transpose.
// Blocks 1024..1279: per-target m-job (argmax, gather+normalize, iv row).
#define BK 64
#define LDK 72   // padded k-stride (bf16) -> 144B col rows; b128 frags 16B-aligned

__global__ __launch_bounds__(256)
void k_big2(const float* __restrict__ video, const unsigned short* __restrict__ snb,
            const float* __restrict__ sn, const float* __restrict__ iou2d,
            const float* __restrict__ iou2ds, const int* __restrict__ idx,
            float* __restrict__ negq, float* __restrict__ iv) {
    __shared__ char smem[36864];
    const int t = threadIdx.x;

    if (blockIdx.x < 1024) {
        // ------------------------------------------------------- GEMM tile
        unsigned short* sA = (unsigned short*)smem;            // [128 rows][LDK]
        unsigned short* vB = (unsigned short*)(smem + 18432);  // [128 cols][LDK]

        const int w    = t >> 6;          // wave 0..3
        const int lane = t & 63;
        const int q    = lane >> 4;       // quad 0..3
        const int l15  = lane & 15;

        const int b  = blockIdx.x >> 5;          // video (tiles never cross videos)
        const int j0 = (blockIdx.x & 31) * 128;  // first flat column of tile

        const int jj = t & 127;           // owned column (lanes consecutive)
        const int kh = t >> 7;            // k-half 0/1 (32 k each)

        f32x4 acc[2][8];
#pragma unroll
        for (int i = 0; i < 2; i++)
#pragma unroll
            for (int j = 0; j < 8; j++) acc[i][j] = (f32x4){0.f, 0.f, 0.f, 0.f};
        float sq = 0.f;                   // per-(col,kh) sumsq partial

        const float* vcol = video + (size_t)b * CC * NSQ + j0 + jj;

        for (int k0 = 0; k0 < CC; k0 += BK) {
            __syncthreads();
            // stage A: 128 sent-rows x 64 k of bf16 (L2-resident snb)
#pragma unroll
            for (int it = 0; it < 4; it++) {
                int lin = t + it * 256;
                int row = lin >> 3, kc = (lin & 7) * 8;
                bf16x8 v = *(const bf16x8*)(snb + (size_t)row * CC + k0 + kc);
                *(bf16x8*)(sA + row * LDK + kc) = v;
            }
            // stage B: per-lane column, scalar k-loads (wave-coalesced),
            // pack 8 -> ds_write_b128 (conflict-free: 36-dword lane stride)
            const float* vp = vcol + (size_t)(k0 + kh * 32) * NSQ;
#pragma unroll
            for (int h = 0; h < 2; h++) {
                float x[16];
#pragma unroll
                for (int i = 0; i < 16; i++) x[i] = vp[(size_t)(h * 16 + i) * NSQ];
#pragma unroll
                for (int g = 0; g < 2; g++) {
                    alignas(16) unsigned short buf[8];
#pragma unroll
                    for (int i = 0; i < 8; i++) {
                        float v = x[g * 8 + i];
                        sq += v * v;
                        buf[i] = f2bf(v);
                    }
                    *(bf16x8*)(vB + jj * LDK + kh * 32 + h * 16 + g * 8) = *(bf16x8*)buf;
                }
            }
            __syncthreads();
            // compute: two K=32 sub-steps
#pragma unroll
            for (int ks = 0; ks < BK; ks += 32) {
                bf16x8 a[2], bfr[8];
#pragma unroll
                for (int rt = 0; rt < 2; rt++) {
                    int row = w * 32 + rt * 16 + l15;
                    a[rt] = *(const bf16x8*)(sA + row * LDK + ks + q * 8);
                }
#pragma unroll
                for (int ct = 0; ct < 8; ct++) {
                    int col = ct * 16 + l15;
                    bfr[ct] = *(const bf16x8*)(vB + col * LDK + ks + q * 8);
                }
#pragma unroll
                for (int rt = 0; rt < 2; rt++)
#pragma unroll
                    for (int ct = 0; ct < 8; ct++)
                        acc[rt][ct] = __builtin_amdgcn_mfma_f32_16x16x32_bf16(
                            a[rt], bfr[ct], acc[rt][ct], 0, 0, 0);
            }
        }
        __syncthreads();   // tile buffers dead; overlay epilogue buffers

        float* sqred = (float*)smem;             // [128][3] = 1536 B (pad 3: no conflict)
        float* redp  = (float*)(smem + 2048);    // [128][17] = 8704 B
        float* colrn = (float*)(smem + 11264);   // [128]     = 512 B

        sqred[jj * 3 + kh] = sq;
        __syncthreads();
        if (t < 128)
            colrn[t] = 1.0f / fmaxf(sqrtf(sqred[t * 3] + sqred[t * 3 + 1]), 1e-12f);
        __syncthreads();

        // epilogue: D layout row = w*32 + rt*16 + q*4 + r, col = ct*16 + l15
#pragma unroll
        for (int rt = 0; rt < 2; rt++) {
#pragma unroll
            for (int r = 0; r < 4; r++) {
                int s = w * 32 + rt * 16 + q * 4 + r;
                bool myvid = ((s >> 2) == b);     // uniform video per tile
                float rowsum = 0.f;
#pragma unroll
                for (int ct = 0; ct < 8; ct++) {
                    int c = ct * 16 + l15;
                    int j = j0 + c;                       // flat N*N index
                    bool valid = (j & 63) >= (j >> 6);    // upper triangle
                    float e = 0.f;
                    if (valid) {
                        float sc = acc[rt][ct][r] * colrn[c];
                        e = expf(sc * 10.0f);             // / T_TEMP
                        if (myvid && iou2d[(size_t)s * NSQ + j] > 0.5f) e = 0.f;
                    }
                    rowsum += e;
                }
                redp[s * 17 + l15] = rowsum;   // unique (s,l15) per lane
            }
        }
        __syncthreads();
        if (t < 128) {
            float tot = 0.f;
#pragma unroll
            for (int x = 0; x < 16; x++) tot += redp[t * 17 + x];
            atomicAdd(&negq[t], tot);
        }
    } else {
        // ------------------------------------------------------- m-job
        const int m = blockIdx.x - 1024;
        float* sv  = (float*)smem;            // [256]
        int*   si  = (int*)(smem + 1024);     // [256]
        float* tvs = (float*)(smem + 2048);   // [512]
        float* red = (float*)(smem + 4096);   // [256]

        // argmax of iou2ds[m] over valid proposals (tie -> lowest p)
        {
            float best = -1e30f; int bi = 1 << 30;
            const float* row = iou2ds + (size_t)m * NSQ;
            for (int p = t; p < PP; p += 256) {
                float v = row[idx[p]];
                if (v > best || (v == best && p < bi)) { best = v; bi = p; }
            }
            sv[t] = best; si[t] = bi;
            __syncthreads();
            for (int off = 128; off > 0; off >>= 1) {
                if (t < off) {
                    float v2 = sv[t + off]; int i2 = si[t + off];
                    if (v2 > sv[t] || (v2 == sv[t] && i2 < si[t])) { sv[t] = v2; si[t] = i2; }
                }
                __syncthreads();
            }
        }
        const int flat = idx[si[0]];
        const int b = m >> 3;                 // scatter_m2v

        // gather + normalize the column
        const float* base = video + (size_t)b * CC * NSQ + flat;
        float x0 = base[(size_t)t * NSQ];
        float x1 = base[(size_t)(t + 256) * NSQ];
        red[t] = x0 * x0 + x1 * x1;
        __syncthreads();
        for (int off = 128; off > 0; off >>= 1) {
            if (t < off) red[t] += red[t + off];
            __syncthreads();
        }
        float rn = 1.0f / fmaxf(sqrtf(red[0]), 1e-12f);
        tvs[t] = x0 * rn;
        tvs[t + 256] = x1 * rn;
        __syncthreads();

        // iv row: thread (s = t&127, h = t>>7) computes half-dot
        const int s = t & 127, h = t >> 7;
        const float4* a4 = (const float4*)(tvs + h * 256);
        const float4* b4 = (const float4*)(sn + (size_t)s * CC + h * 256);
        float acc2 = 0.f;
#pragma unroll 8
        for (int c = 0; c < 64; c++) {
            float4 a = a4[c], bb = b4[c];
            acc2 += a.x * bb.x + a.y * bb.y + a.z * bb.z + a.w * bb.w;
        }
        __syncthreads();          // red reuse
        red[t] = acc2;
        __syncthreads();
        if (t < 128) iv[(size_t)m * SS + t] = red[t] + red[t + 128];
    }
}

// ---------------------------------------------------------------------------
// final losses
__global__ void k_final(const float* __restrict__ iv, const float* __restrict__ negq,
                        float* __restrict__ out) {
    const int t = threadIdx.x;   // 256 = M
    __shared__ float rv[256], rq[256];
    const float* row = iv + (size_t)t * SS;
    const int ms = t >> 1;       // scatter_m2s
    float pos = row[ms];
    float nv = 0.f;
    for (int s = 0; s < SS; s++) {
        float e = expf(row[s] * 10.0f);
        if (s == ms) e = 0.f;
        nv += e;
    }
    float pe = expf(pos * 10.0f);
    float lv = logf(pe + nv) - pos * 10.0f;
    float lq = logf(pe + negq[ms]) - pos * 10.0f;
    rv[t] = lv; rq[t] = lq;
    __syncthreads();
    for (int off = 128; off > 0; off >>= 1) {
        if (t < off) { rv[t] += rv[t + off]; rq[t] += rq[t + off]; }
        __syncthreads();
    }
    if (t == 0) {
        float liv = rv[0] / 256.f, liq = rq[0] / 256.f;
        out[0] = liv + liq;   // total (WEIGHT=1)
        out[1] = liv;
        out[2] = liq;
    }
}

// ---------------------------------------------------------------------------
extern "C" void kernel_launch(void* const* d_in, const int* in_sizes, int n_in,
                              void* d_out, int out_size, void* d_ws, size_t ws_size,
                              hipStream_t stream) {
    const float* video  = (const float*)d_in[0];   // (B,C,N,N)
    const float* sents  = (const float*)d_in[1];   // (S,C)
    const float* iou2d  = (const float*)d_in[4];   // (S,N,N)
    const float* iou2ds = (const float*)d_in[5];   // (M,N,N)
    float* out = (float*)d_out;

    char* ws = (char*)d_ws;
    float*          sn   = (float*)(ws + WS_SN);
    unsigned short* snb  = (unsigned short*)(ws + WS_SNB);
    int*            idx  = (int*)(ws + WS_IDX);
    float*          iv   = (float*)(ws + WS_IV);
    float*          negq = (float*)(ws + WS_NEGQ);

    k_prep <<<145, 256, 0, stream>>>(sents, sn, snb, idx, negq);
    k_big2 <<<1024 + MM, 256, 0, stream>>>(video, snb, sn, iou2d, iou2ds, idx, negq, iv);
    k_final<<<1, 256, 0, stream>>>(iv, negq, out);
}

// Round 4
// 412.379 us; speedup vs baseline: 1.3081x; 1.0195x over previous
//
#include <hip/hip_runtime.h>
#include <cstdint>

// Static problem sizes
#define BB 32
#define CC 512
#define NSQ 4096      // N*N
#define SS 128
#define MM 256
#define PP 2080
#define TPV 17        // triangle tiles per video: ceil(2080/128)

// ws layout (byte offsets)
#define WS_SN     0         // sents_norm fp32: 128*512*4 = 262144
#define WS_SNB    262144    // sents_norm bf16: 128*512*2 = 131072
#define WS_IDX    393216    // idx: 2080 i32 = 8320
#define WS_IV     401536    // iv_all: 256*128*4 = 131072
#define WS_NEGQ   532608    // neg_sum_q: 128*4 = 512

typedef short bf16x8 __attribute__((ext_vector_type(8)));   // 8 bf16 raw (4 VGPRs)
typedef float f32x4  __attribute__((ext_vector_type(4)));   // MFMA accumulator

__device__ __forceinline__ unsigned short f2bf(float x) {
    unsigned int u = __float_as_uint(x);
    unsigned int r = (u + 0x7fffu + ((u >> 16) & 1u)) >> 16;   // RNE
    return (unsigned short)r;
}

// ---------------------------------------------------------------------------
// prep: blocks 0..127 normalize sents rows (fp32 + bf16 copies);
//       128..143 build idx table; 144 zeroes negq.
__global__ void k_prep(const float* __restrict__ sents, float* __restrict__ sn,
                       unsigned short* __restrict__ snb,
                       int* __restrict__ idx, float* __restrict__ negq) {
    const int blk = blockIdx.x, t = threadIdx.x;
    if (blk < 128) {
        __shared__ float red[256];
        const float* row = sents + (size_t)blk * CC;
        float x0 = row[t], x1 = row[t + 256];
        red[t] = x0 * x0 + x1 * x1;
        __syncthreads();
        for (int off = 128; off > 0; off >>= 1) {
            if (t < off) red[t] += red[t + off];
            __syncthreads();
        }
        float rn = 1.0f / fmaxf(sqrtf(red[0]), 1e-12f);
        float y0 = x0 * rn, y1 = x1 * rn;
        sn[(size_t)blk * CC + t]        = y0;
        sn[(size_t)blk * CC + t + 256]  = y1;
        snb[(size_t)blk * CC + t]       = f2bf(y0);
        snb[(size_t)blk * CC + t + 256] = f2bf(y1);
    } else if (blk < 144) {
        int i = (blk - 128) * 256 + t;      // 0..4095
        int r = i >> 6, c = i & 63;
        if (c >= r) {
            int p = r * 64 - (r * (r - 1)) / 2 + (c - r);
            idx[p] = i;
        }
    } else {
        if (t < 128) negq[t] = 0.0f;
    }
}

// ---------------------------------------------------------------------------
// Merged big kernel, 800 blocks (one fully co-resident set at 4 blocks/CU).
// Blocks 0..255: per-target m-jobs (latency-bound; overlap the GEMM stream).
// Blocks 256..799: triangle-tiled score GEMM. Tile = video b x 128 columns in
//   COMPACTED p-space (p0 = tp*128) -> per-lane flat columns are consecutive
//   within each triangle row segment => near-dense loads, only valid data
//   fetched (~167MB vs 268MB dense). Tail tile (tp=16) has 32 valid cols.
// B transpose: lane owns one column, packs bf16x8, ds_write_b128 at
//   col*LDK (36-dword lane stride => bank-conflict-free).
#define BK 64
#define LDK 72   // padded k-stride (bf16) -> 144B col rows; b128 frags 16B-aligned

__global__ __launch_bounds__(256)
void k_big3(const float* __restrict__ video, const unsigned short* __restrict__ snb,
            const float* __restrict__ sn, const float* __restrict__ iou2d,
            const float* __restrict__ iou2ds, const int* __restrict__ idx,
            float* __restrict__ negq, float* __restrict__ iv) {
    __shared__ char smem[36864];
    const int t = threadIdx.x;

    if (blockIdx.x >= MM) {
        // ------------------------------------------------------- GEMM tile
        unsigned short* sA = (unsigned short*)smem;            // [128 rows][LDK]
        unsigned short* vB = (unsigned short*)(smem + 18432);  // [128 cols][LDK]

        const int w    = t >> 6;          // wave 0..3
        const int lane = t & 63;
        const int q    = lane >> 4;       // quad 0..3
        const int l15  = lane & 15;

        const int gid = blockIdx.x - MM;  // 0..543
        const int b   = gid / TPV;        // video
        const int p0  = (gid - b * TPV) * 128;   // first compacted column

        const int jj = t & 127;           // owned local column (lanes consecutive)
        const int kh = t >> 7;            // k-half 0/1 (32 k each)

        const int pcol = p0 + jj;
        const int flat = idx[pcol < PP ? pcol : PP - 1];   // clamp tail
        const float* vcol = video + (size_t)b * CC * NSQ + flat;

        f32x4 acc[2][8];
#pragma unroll
        for (int i = 0; i < 2; i++)
#pragma unroll
            for (int j = 0; j < 8; j++) acc[i][j] = (f32x4){0.f, 0.f, 0.f, 0.f};
        float sq = 0.f;                   // per-(col,kh) sumsq partial

        for (int k0 = 0; k0 < CC; k0 += BK) {
            __syncthreads();
            // stage A: 128 sent-rows x 64 k of bf16 (L2-resident snb)
#pragma unroll
            for (int it = 0; it < 4; it++) {
                int lin = t + it * 256;
                int row = lin >> 3, kc = (lin & 7) * 8;
                bf16x8 v = *(const bf16x8*)(snb + (size_t)row * CC + k0 + kc);
                *(bf16x8*)(sA + row * LDK + kc) = v;
            }
            // stage B: per-lane column, scalar k-loads (segment-dense),
            // pack 8 -> ds_write_b128 (conflict-free)
            const float* vp = vcol + (size_t)(k0 + kh * 32) * NSQ;
#pragma unroll
            for (int h = 0; h < 2; h++) {
                float x[16];
#pragma unroll
                for (int i = 0; i < 16; i++) x[i] = vp[(size_t)(h * 16 + i) * NSQ];
#pragma unroll
                for (int g = 0; g < 2; g++) {
                    alignas(16) unsigned short buf[8];
#pragma unroll
                    for (int i = 0; i < 8; i++) {
                        float v = x[g * 8 + i];
                        sq += v * v;
                        buf[i] = f2bf(v);
                    }
                    *(bf16x8*)(vB + jj * LDK + kh * 32 + h * 16 + g * 8) = *(bf16x8*)buf;
                }
            }
            __syncthreads();
            // compute: two K=32 sub-steps
#pragma unroll
            for (int ks = 0; ks < BK; ks += 32) {
                bf16x8 a[2], bfr[8];
#pragma unroll
                for (int rt = 0; rt < 2; rt++) {
                    int row = w * 32 + rt * 16 + l15;
                    a[rt] = *(const bf16x8*)(sA + row * LDK + ks + q * 8);
                }
#pragma unroll
                for (int ct = 0; ct < 8; ct++) {
                    int col = ct * 16 + l15;
                    bfr[ct] = *(const bf16x8*)(vB + col * LDK + ks + q * 8);
                }
#pragma unroll
                for (int rt = 0; rt < 2; rt++)
#pragma unroll
                    for (int ct = 0; ct < 8; ct++)
                        acc[rt][ct] = __builtin_amdgcn_mfma_f32_16x16x32_bf16(
                            a[rt], bfr[ct], acc[rt][ct], 0, 0, 0);
            }
        }
        __syncthreads();   // tile buffers dead; overlay epilogue buffers

        float* sqred   = (float*)smem;             // [128][3] = 1536 B
        float* colrn   = (float*)(smem + 1536);    // [128]    = 512 B
        int*   colflat = (int*)(smem + 2048);      // [128]    = 512 B
        float* redp    = (float*)(smem + 2560);    // [128][17]= 8704 B

        sqred[jj * 3 + kh] = sq;
        if (t < 128) {
            int p = p0 + t;
            colflat[t] = idx[p < PP ? p : PP - 1];
        }
        __syncthreads();
        if (t < 128)
            colrn[t] = 1.0f / fmaxf(sqrtf(sqred[t * 3] + sqred[t * 3 + 1]), 1e-12f);
        __syncthreads();

        // epilogue: D layout row = w*32 + rt*16 + q*4 + r, col = ct*16 + l15
#pragma unroll
        for (int rt = 0; rt < 2; rt++) {
#pragma unroll
            for (int r = 0; r < 4; r++) {
                int s = w * 32 + rt * 16 + q * 4 + r;
                bool myvid = ((s >> 2) == b);     // uniform video per tile
                float rowsum = 0.f;
#pragma unroll
                for (int ct = 0; ct < 8; ct++) {
                    int c = ct * 16 + l15;
                    float e = 0.f;
                    if (p0 + c < PP) {                    // valid compacted col
                        float sc = acc[rt][ct][r] * colrn[c];
                        e = expf(sc * 10.0f);             // / T_TEMP
                        if (myvid && iou2d[(size_t)s * NSQ + colflat[c]] > 0.5f) e = 0.f;
                    }
                    rowsum += e;
                }
                redp[s * 17 + l15] = rowsum;   // unique (s,l15) per lane
            }
        }
        __syncthreads();
        if (t < 128) {
            float tot = 0.f;
#pragma unroll
            for (int x = 0; x < 16; x++) tot += redp[t * 17 + x];
            atomicAdd(&negq[t], tot);
        }
    } else {
        // ------------------------------------------------------- m-job
        const int m = blockIdx.x;
        float* sv  = (float*)smem;            // [256]
        int*   si  = (int*)(smem + 1024);     // [256]
        float* tvs = (float*)(smem + 2048);   // [512]
        float* red = (float*)(smem + 4096);   // [256]

        // argmax of iou2ds[m] over valid proposals (tie -> lowest p)
        {
            float best = -1e30f; int bi = 1 << 30;
            const float* row = iou2ds + (size_t)m * NSQ;
            for (int p = t; p < PP; p += 256) {
                float v = row[idx[p]];
                if (v > best || (v == best && p < bi)) { best = v; bi = p; }
            }
            sv[t] = best; si[t] = bi;
            __syncthreads();
            for (int off = 128; off > 0; off >>= 1) {
                if (t < off) {
                    float v2 = sv[t + off]; int i2 = si[t + off];
                    if (v2 > sv[t] || (v2 == sv[t] && i2 < si[t])) { sv[t] = v2; si[t] = i2; }
                }
                __syncthreads();
            }
        }
        const int flat = idx[si[0]];
        const int b = m >> 3;                 // scatter_m2v

        // gather + normalize the column
        const float* base = video + (size_t)b * CC * NSQ + flat;
        float x0 = base[(size_t)t * NSQ];
        float x1 = base[(size_t)(t + 256) * NSQ];
        red[t] = x0 * x0 + x1 * x1;
        __syncthreads();
        for (int off = 128; off > 0; off >>= 1) {
            if (t < off) red[t] += red[t + off];
            __syncthreads();
        }
        float rn = 1.0f / fmaxf(sqrtf(red[0]), 1e-12f);
        tvs[t] = x0 * rn;
        tvs[t + 256] = x1 * rn;
        __syncthreads();

        // iv row: thread (s = t&127, h = t>>7) computes half-dot
        const int s = t & 127, h = t >> 7;
        const float4* a4 = (const float4*)(tvs + h * 256);
        const float4* b4 = (const float4*)(sn + (size_t)s * CC + h * 256);
        float acc2 = 0.f;
#pragma unroll 8
        for (int c = 0; c < 64; c++) {
            float4 a = a4[c], bb = b4[c];
            acc2 += a.x * bb.x + a.y * bb.y + a.z * bb.z + a.w * bb.w;
        }
        __syncthreads();          // red reuse
        red[t] = acc2;
        __syncthreads();
        if (t < 128) iv[(size_t)m * SS + t] = red[t] + red[t + 128];
    }
}

// ---------------------------------------------------------------------------
// final losses
__global__ void k_final(const float* __restrict__ iv, const float* __restrict__ negq,
                        float* __restrict__ out) {
    const int t = threadIdx.x;   // 256 = M
    __shared__ float rv[256], rq[256];
    const float* row = iv + (size_t)t * SS;
    const int ms = t >> 1;       // scatter_m2s
    float pos = row[ms];
    float nv = 0.f;
    for (int s = 0; s < SS; s++) {
        float e = expf(row[s] * 10.0f);
        if (s == ms) e = 0.f;
        nv += e;
    }
    float pe = expf(pos * 10.0f);
    float lv = logf(pe + nv) - pos * 10.0f;
    float lq = logf(pe + negq[ms]) - pos * 10.0f;
    rv[t] = lv; rq[t] = lq;
    __syncthreads();
    for (int off = 128; off > 0; off >>= 1) {
        if (t < off) { rv[t] += rv[t + off]; rq[t] += rq[t + off]; }
        __syncthreads();
    }
    if (t == 0) {
        float liv = rv[0] / 256.f, liq = rq[0] / 256.f;
        out[0] = liv + liq;   // total (WEIGHT=1)
        out[1] = liv;
        out[2] = liq;
    }
}

// ---------------------------------------------------------------------------
extern "C" void kernel_launch(void* const* d_in, const int* in_sizes, int n_in,
                              void* d_out, int out_size, void* d_ws, size_t ws_size,
                              hipStream_t stream) {
    const float* video  = (const float*)d_in[0];   // (B,C,N,N)
    const float* sents  = (const float*)d_in[1];   // (S,C)
    const float* iou2d  = (const float*)d_in[4];   // (S,N,N)
    const float* iou2ds = (const float*)d_in[5];   // (M,N,N)
    float* out = (float*)d_out;

    char* ws = (char*)d_ws;
    float*          sn   = (float*)(ws + WS_SN);
    unsigned short* snb  = (unsigned short*)(ws + WS_SNB);
    int*            idx  = (int*)(ws + WS_IDX);
    float*          iv   = (float*)(ws + WS_IV);
    float*          negq = (float*)(ws + WS_NEGQ);

    k_prep <<<145, 256, 0, stream>>>(sents, sn, snb, idx, negq);
    k_big3 <<<MM + BB * TPV, 256, 0, stream>>>(video, snb, sn, iou2d, iou2ds, idx, negq, iv);
    k_final<<<1, 256, 0, stream>>>(iv, negq, out);
}